// Round 1
// baseline (749.761 us; speedup 1.0000x reference)
//
#include <hip/hip_runtime.h>
#include <hip/hip_fp16.h>
#include <math.h>

#define BATCH      32
#define CHUNK      128
#define NCHUNK     500      // 64000 / 128
#define SLABSTRIDE 66       // halves per row: 64 used + 2 pad -> conflict-free banks

// ---------------------------------------------------------------------------
// 256 * scale_fn(x) = 512*(1+e^-x)^(-ln10) + 256e-7, exact transcendental form.
// x->+inf: e=0, l=0 -> 512.0; x->-inf: e=inf, l=inf, exp2(-inf)=0 -> 2.56e-5. Graceful.
// ---------------------------------------------------------------------------
__device__ __forceinline__ float scale256(float x) {
    float e = exp2f(-1.4426950408889634f * x);       // e^{-x}
    float l = log2f(1.0f + e);
    return fmaf(512.0f, exp2f(-2.302585092994046f * l), 256.0f * 1e-7f);
}

// ---------------------------------------------------------------------------
// Kernel 1: per-chunk sums of f0 in double. grid = BATCH*NCHUNK blocks x 128.
// ---------------------------------------------------------------------------
__global__ __launch_bounds__(128) void chunk_sum_kernel(
        const float* __restrict__ f0, double* __restrict__ csum) {
    int bx = blockIdx.x;
    int t  = threadIdx.x;
    double v = (double)f0[(long)bx * CHUNK + t];
    for (int off = 32; off > 0; off >>= 1) v += __shfl_down(v, off, 64);
    __shared__ double ws[2];
    if ((t & 63) == 0) ws[t >> 6] = v;
    __syncthreads();
    if (t == 0) csum[bx] = ws[0] + ws[1];
}

// ---------------------------------------------------------------------------
// Kernel 2: per-row EXCLUSIVE scan of the NCHUNK chunk sums (in place).
// ---------------------------------------------------------------------------
__global__ __launch_bounds__(512) void chunk_scan_kernel(double* __restrict__ csum) {
    int r = blockIdx.x;
    int t = threadIdx.x;
    int lane = t & 63, w = t >> 6;
    double orig = (t < NCHUNK) ? csum[(long)r * NCHUNK + t] : 0.0;
    double v = orig;
    for (int off = 1; off < 64; off <<= 1) {
        double n = __shfl_up(v, off, 64);
        if (lane >= off) v += n;
    }
    __shared__ double wsum[8];
    if (lane == 63) wsum[w] = v;
    __syncthreads();
    double add = 0.0;
    for (int i = 0; i < w; ++i) add += wsum[i];
    v += add;
    if (t < NCHUNK) csum[(long)r * NCHUNK + t] = v - orig;   // exclusive prefix
}

// ---------------------------------------------------------------------------
// Staging helper: 4 consecutive flat slab elements e..e+3 (e = s*65 + c).
//   c == 0 : total amplitude -> amp0[s] = wv/256 (f32, exact scale_fn)
//   c >= 1 : wv256 * antialias-mask -> fp16 at slab[s*66 + c-1]
// Mask (f0*c < 22050 in f32) is bit-identical to the reference's aa.
// ---------------------------------------------------------------------------
__device__ __forceinline__ void process4(float4 v, int e,
        __half* __restrict__ slab, float* __restrict__ amp0,
        const float* __restrict__ f0s) {
    int s = e / 65;
    int c = e - s * 65;
    float vals[4] = {v.x, v.y, v.z, v.w};
    #pragma unroll
    for (int k = 0; k < 4; ++k) {
        float wv = scale256(vals[k]);
        if (c == 0) {
            amp0[s] = wv * 0.00390625f;              // /256, exact
        } else {
            bool keep = f0s[s] * (float)c < 22050.0f;
            slab[s * SLABSTRIDE + (c - 1)] = __float2half(keep ? wv : 0.0f);
        }
        if (++c == 65) { c = 0; ++s; }
    }
}

// ---------------------------------------------------------------------------
// Kernel 3: main oscillator. One block = 128 consecutive samples of one row.
// - scale_fn + anti-alias mask folded into the (ILP-rich) staging pass
// - weights stored x256 in fp16, stride-66 rows: conflict-free half2 ds_read
// - LDS ~17.9 KB/block -> 8 blocks/CU (was 38 KB -> 4 blocks/CU)
// - sin((h+1)θ) via Chebyshev: 1 fma per harmonic (was 4-fma rotation)
// ---------------------------------------------------------------------------
__global__ __launch_bounds__(128, 4) void osc_kernel(
        const float* __restrict__ f0,
        const float* __restrict__ ha,
        const float* __restrict__ phase,
        const double* __restrict__ csum,
        float* __restrict__ out) {
    int bx = blockIdx.x;
    int r  = bx / NCHUNK;
    int t  = threadIdx.x;
    int lane = t & 63, w = t >> 6;

    long sbase = (long)bx * CHUNK;

    __shared__ __half slab[CHUNK * SLABSTRIDE];   // 16,896 B
    __shared__ float  amp0[CHUNK];                //    512 B
    __shared__ float  f0s[CHUNK];                 //    512 B
    __shared__ double wsum[2];                    //     16 B

    // ---- stage f0 (needed by the anti-alias mask below) ----
    if (t < 32) ((float4*)f0s)[t] = ((const float4*)(f0 + sbase))[t];
    __syncthreads();

    // ---- staging: contiguous coalesced float4 reads, fused scale_fn+mask ----
    const float4* src = (const float4*)(ha + sbase * 65);   // 33,280 B, 16B-aligned
    #pragma unroll 4
    for (int i = 0; i < 16; ++i) {
        float4 v = src[i * 128 + t];
        process4(v, (i * 128 + t) * 4, slab, amp0, f0s);
    }
    if (t < 32) {
        float4 v = src[2048 + t];
        process4(v, (2048 + t) * 4, slab, amp0, f0s);
    }

    // ---- inclusive scan of f0 in double -> nu (revolutions, mod 1) ----
    float f0v = f0s[t];
    double v = (double)f0v;
    for (int off = 1; off < 64; off <<= 1) {
        double n = __shfl_up(v, off, 64);
        if (lane >= off) v += n;
    }
    if (lane == 63) wsum[w] = v;
    __syncthreads();                    // covers slab/amp0 writes + wsum
    if (w == 1) v += wsum[0];
    v += csum[bx];
    double x = v * (1.0 / 44100.0) + (double)phase[r] * 0.15915494309189535;
    x -= floor(x);
    float nu = (float)x;                // [0,1)

    // ---- Chebyshev recurrence: s_{h+1} = 2cosθ·s_h − s_{h−1} ----
    float th = 6.283185307179586f * nu;
    float sA = __sinf(th);              // sin(1θ)
    float c2 = 2.0f * __cosf(th);
    float sB = c2 * sA;                 // sin(2θ) = 2 sinθ cosθ

    float S1 = 0.0f, S2 = 0.0f;
    const __half2* row = (const __half2*)(slab + t * SLABSTRIDE);  // 4B-aligned
    #pragma unroll
    for (int j = 0; j < 32; ++j) {
        float2 w2 = __half22float2(row[j]);        // harmonics c=2j+1, 2j+2
        S1 += w2.x; S2 = fmaf(w2.x, sA, S2);
        S1 += w2.y; S2 = fmaf(w2.y, sB, S2);
        float sn1 = fmaf(c2, sB, -sA);             // sin((2j+3)θ)
        float sn2 = fmaf(c2, sn1, -sB);            // sin((2j+4)θ)
        sA = sn1; sB = sn2;
    }

    // weights were x256: S1,S2 both scaled, so use eps*256 — ratio exact.
    out[sbase + t] = amp0[t] * S2 / (S1 + 256.0f * 1e-5f);
}

// ---------------------------------------------------------------------------
extern "C" void kernel_launch(void* const* d_in, const int* in_sizes, int n_in,
                              void* d_out, int out_size, void* d_ws, size_t ws_size,
                              hipStream_t stream) {
    (void)in_sizes; (void)n_in; (void)out_size; (void)ws_size;
    const float* f0    = (const float*)d_in[0];   // (32, 64000)
    const float* ha    = (const float*)d_in[1];   // (32, 64000, 65)
    const float* phase = (const float*)d_in[2];   // (32,)
    float* out = (float*)d_out;                   // (32, 64000)

    double* csum = (double*)d_ws;                 // 16000 doubles = 128 KB

    chunk_sum_kernel<<<BATCH * NCHUNK, CHUNK, 0, stream>>>(f0, csum);
    chunk_scan_kernel<<<BATCH, 512, 0, stream>>>(csum);
    osc_kernel<<<BATCH * NCHUNK, CHUNK, 0, stream>>>(f0, ha, phase, csum, out);
}

// Round 2
// 692.427 us; speedup vs baseline: 1.0828x; 1.0828x over previous
//
#include <hip/hip_runtime.h>
#include <math.h>

#define BATCH    32
#define CHUNK    128
#define NCHUNK   500      // 64000 / 128
#define TAB_N    1152     // 9*128 floats; entries 0..1023 cover x in [-8,8), rest pad

// ---------------------------------------------------------------------------
// exact scale function: 2 * sigmoid(x)^ln(10) + 1e-7 = 2*(1+e^-x)^(-ln10)+1e-7
// ---------------------------------------------------------------------------
__device__ __forceinline__ float scale_fn(float x) {
    float e = exp2f(-1.4426950408889634f * x);       // e^{-x}
    float l = log2f(1.0f + e);
    return 2.0f * exp2f(-2.302585092994046f * l) + 1e-7f;
}

// ---------------------------------------------------------------------------
// Kernel 0: build the scale_fn lookup table in global ws (rebuilt every call —
// harness re-poisons ws). Entry i = scale_fn(-8 + i/64).
// ---------------------------------------------------------------------------
__global__ __launch_bounds__(128) void table_kernel(float* __restrict__ gtab) {
    int i = blockIdx.x * 128 + threadIdx.x;
    if (i < TAB_N) gtab[i] = scale_fn(fmaf((float)i, 0.015625f, -8.0f));
}

// ---------------------------------------------------------------------------
// Kernel 1: per-chunk sums of f0 in double. grid = BATCH*NCHUNK blocks x 128.
// ---------------------------------------------------------------------------
__global__ __launch_bounds__(128) void chunk_sum_kernel(
        const float* __restrict__ f0, double* __restrict__ csum) {
    int bx = blockIdx.x;
    int t  = threadIdx.x;
    double v = (double)f0[(long)bx * CHUNK + t];
    for (int off = 32; off > 0; off >>= 1) v += __shfl_down(v, off, 64);
    __shared__ double ws[2];
    if ((t & 63) == 0) ws[t >> 6] = v;
    __syncthreads();
    if (t == 0) csum[bx] = ws[0] + ws[1];
}

// ---------------------------------------------------------------------------
// Kernel 2: per-row EXCLUSIVE scan of the NCHUNK chunk sums (in place).
// ---------------------------------------------------------------------------
__global__ __launch_bounds__(512) void chunk_scan_kernel(double* __restrict__ csum) {
    int r = blockIdx.x;
    int t = threadIdx.x;
    int lane = t & 63, w = t >> 6;
    double orig = (t < NCHUNK) ? csum[(long)r * NCHUNK + t] : 0.0;
    double v = orig;
    for (int off = 1; off < 64; off <<= 1) {
        double n = __shfl_up(v, off, 64);
        if (lane >= off) v += n;
    }
    __shared__ double wsum[8];
    if (lane == 63) wsum[w] = v;
    __syncthreads();
    double add = 0.0;
    for (int i = 0; i < w; ++i) add += wsum[i];
    v += add;
    if (t < NCHUNK) csum[(long)r * NCHUNK + t] = v - orig;   // exclusive prefix
}

// ---------------------------------------------------------------------------
// Kernel 3: main oscillator. One block = 512 threads = 128 samples x 4 lane
// quarters; each lane handles 16 of the 64 harmonics of its sample.
// vs the 703us version:
//   - staging / table / mask math byte-identical (proven absmax)
//   - serial per-lane chain is 16 iters instead of 64 (4x shorter)
//   - 8-wave blocks: 4 blocks/CU -> up to 32 waves/CU (was 8)
//   - Chebyshev sin recurrence: 1 fma per harmonic (was 4-fma rotation)
// ---------------------------------------------------------------------------
__global__ __launch_bounds__(512, 4) void osc_kernel(
        const float* __restrict__ f0,
        const float* __restrict__ ha,
        const float* __restrict__ phase,
        const double* __restrict__ csum,
        const float* __restrict__ gtab,
        float* __restrict__ out) {
    int bx = blockIdx.x;
    int r  = bx / NCHUNK;
    int t  = threadIdx.x;
    int lane = t & 63, w = t >> 6;          // wave 0..7

    long sbase = (long)bx * CHUNK;
    const float* hablk = ha + sbase * 65;

    __shared__ float  amp[CHUNK * 65];      // 33,280 B
    __shared__ float  tab[TAB_N];           //  4,608 B
    __shared__ float  f0s[CHUNK];           //    512 B
    __shared__ float  nuA[CHUNK];           //    512 B
    __shared__ double wsum[2];

    // ---- stage table (288 float4), f0 (32 float4), amp slab (2080 float4) ----
    if (t < 288) ((float4*)tab)[t] = ((const float4*)gtab)[t];
    if (t < 32)  ((float4*)f0s)[t] = ((const float4*)(f0 + sbase))[t];
    {
        const float4* src = (const float4*)hablk;
        float4* dst = (float4*)amp;
        #pragma unroll
        for (int i = 0; i < 4; ++i)
            dst[i * 512 + t] = src[i * 512 + t];
        if (t < 32) dst[2048 + t] = src[2048 + t];
    }
    __syncthreads();

    // ---- inclusive scan of f0 in double -> nu (revolutions, mod 1) ----
    // done by the first 128 threads (2 waves); others wait at the barriers
    double v = 0.0;
    if (t < 128) {
        v = (double)f0s[t];
        for (int off = 1; off < 64; off <<= 1) {
            double n = __shfl_up(v, off, 64);
            if (lane >= off) v += n;
        }
        if (lane == 63) wsum[w] = v;
    }
    __syncthreads();
    if (t < 128) {
        if (w == 1) v += wsum[0];
        v += csum[bx];
        double x = v * (1.0 / 44100.0) + (double)phase[r] * 0.15915494309189535;
        x -= floor(x);
        nuA[t] = (float)x;                  // [0,1)
    }
    __syncthreads();

    // ---- per-lane assignment: sample s, harmonic quarter q ----
    int s  = w * 16 + (lane & 15);          // sample within chunk
    int q  = lane >> 4;                     // 0..3
    int h0 = q * 16;                        // harmonics h0+1 .. h0+16

    float f0v = f0s[s];
    float nu  = nuA[s];

    // ---- exact anti-alias cutoff: max h with f0*h < 22050 (f32 semantics) ----
    float k0 = floorf(22050.0f / f0v);
    if (f0v * (k0 + 1.0f) < 22050.0f)      k0 += 1.0f;
    else if (!(f0v * k0 < 22050.0f))       k0 -= 1.0f;

    // ---- Chebyshev recurrence init: sA=sin((h0+1)θ), sB=sin((h0+2)θ) ----
    float c2;
    {
        float th = 6.283185307179586f * nu;
        c2 = 2.0f * __cosf(th);
    }
    float m1 = (float)(h0 + 1) * nu; m1 -= floorf(m1);
    float m2 = (float)(h0 + 2) * nu; m2 -= floorf(m2);
    float sA = __sinf(6.283185307179586f * m1);
    float sB = 6.283185307179586f * m2;  sB = __sinf(sB);

    const float* arow = amp + s * 65 + 1 + h0;

    float S1 = 0.0f, S2 = 0.0f;
    #pragma unroll
    for (int j = 0; j < 16; j += 2) {
        float a0 = arow[j];
        float a1 = arow[j + 1];
        // scale_fn via table interp (identical math to the 703us version)
        float tc0 = fmaf(a0, 64.0f, 512.0f);
        tc0 = fminf(fmaxf(tc0, 0.0f), 1022.99f);
        float fi0 = floorf(tc0); int i0 = (int)fi0; float fr0 = tc0 - fi0;
        float w0 = fmaf(fr0, tab[i0 + 1] - tab[i0], tab[i0]);
        float tc1 = fmaf(a1, 64.0f, 512.0f);
        tc1 = fminf(fmaxf(tc1, 0.0f), 1022.99f);
        float fi1 = floorf(tc1); int i1 = (int)fi1; float fr1 = tc1 - fi1;
        float w1 = fmaf(fr1, tab[i1 + 1] - tab[i1], tab[i1]);

        w0 = ((float)(h0 + 1 + j) <= k0) ? w0 : 0.0f;
        w1 = ((float)(h0 + 2 + j) <= k0) ? w1 : 0.0f;

        S1 += w0; S2 = fmaf(w0, sA, S2);
        S1 += w1; S2 = fmaf(w1, sB, S2);

        float sn1 = fmaf(c2, sB, -sA);       // sin((h0+3+j)θ)
        float sn2 = fmaf(c2, sn1, -sB);      // sin((h0+4+j)θ)
        sA = sn1; sB = sn2;
    }

    // ---- combine the 4 harmonic quarters of each sample ----
    S1 += __shfl_xor(S1, 16, 64);
    S1 += __shfl_xor(S1, 32, 64);
    S2 += __shfl_xor(S2, 16, 64);
    S2 += __shfl_xor(S2, 32, 64);

    if (q == 0) {
        float total = scale_fn(amp[s * 65]);           // exact, once per sample
        out[sbase + s] = total * S2 / (S1 + 1e-5f);
    }
}

// ---------------------------------------------------------------------------
extern "C" void kernel_launch(void* const* d_in, const int* in_sizes, int n_in,
                              void* d_out, int out_size, void* d_ws, size_t ws_size,
                              hipStream_t stream) {
    (void)in_sizes; (void)n_in; (void)out_size; (void)ws_size;
    const float* f0    = (const float*)d_in[0];   // (32, 64000)
    const float* ha    = (const float*)d_in[1];   // (32, 64000, 65)
    const float* phase = (const float*)d_in[2];   // (32,)
    float* out = (float*)d_out;                   // (32, 64000)

    double* csum = (double*)d_ws;                            // 16000 doubles = 128 KB
    float*  gtab = (float*)((char*)d_ws + 131072);           // table after csum

    table_kernel<<<(TAB_N + 127) / 128, 128, 0, stream>>>(gtab);
    chunk_sum_kernel<<<BATCH * NCHUNK, CHUNK, 0, stream>>>(f0, csum);
    chunk_scan_kernel<<<BATCH, 512, 0, stream>>>(csum);
    osc_kernel<<<BATCH * NCHUNK, 512, 0, stream>>>(f0, ha, phase, csum, gtab, out);
}

// Round 3
// 678.572 us; speedup vs baseline: 1.1049x; 1.0204x over previous
//
#include <hip/hip_runtime.h>
#include <math.h>

#define BATCH    32
#define CHUNK    128
#define NCHUNK   500                      // 64000 / 128
#define NCH_TOT  (BATCH * NCHUNK)         // 16000 chunks
#define TAB_N    1152                     // 9*128 floats; 0..1023 cover [-8,8)
#define PBLOCKS  512                      // persistent grid: 2 blocks/CU x 256 CU

// ---------------------------------------------------------------------------
// exact scale function: 2 * sigmoid(x)^ln(10) + 1e-7 = 2*(1+e^-x)^(-ln10)+1e-7
// ---------------------------------------------------------------------------
__device__ __forceinline__ float scale_fn(float x) {
    float e = exp2f(-1.4426950408889634f * x);       // e^{-x}
    float l = log2f(1.0f + e);
    return 2.0f * exp2f(-2.302585092994046f * l) + 1e-7f;
}

// async global->LDS, 16B per lane (guide-sanctioned AS-cast form)
#define GLOAD_LDS16(g, l)  __builtin_amdgcn_global_load_lds(                 \
    (const __attribute__((address_space(1))) void*)(g),                      \
    (__attribute__((address_space(3))) void*)(l), 16, 0, 0)

// ---------------------------------------------------------------------------
// Kernel 0: scale_fn lookup table (rebuilt every call; ws is re-poisoned).
// ---------------------------------------------------------------------------
__global__ __launch_bounds__(128) void table_kernel(float* __restrict__ gtab) {
    int i = blockIdx.x * 128 + threadIdx.x;
    if (i < TAB_N) gtab[i] = scale_fn(fmaf((float)i, 0.015625f, -8.0f));
}

// ---------------------------------------------------------------------------
// Kernel 1: per-chunk sums of f0 in double.
// ---------------------------------------------------------------------------
__global__ __launch_bounds__(128) void chunk_sum_kernel(
        const float* __restrict__ f0, double* __restrict__ csum) {
    int bx = blockIdx.x;
    int t  = threadIdx.x;
    double v = (double)f0[(long)bx * CHUNK + t];
    for (int off = 32; off > 0; off >>= 1) v += __shfl_down(v, off, 64);
    __shared__ double ws[2];
    if ((t & 63) == 0) ws[t >> 6] = v;
    __syncthreads();
    if (t == 0) csum[bx] = ws[0] + ws[1];
}

// ---------------------------------------------------------------------------
// Kernel 2: per-row EXCLUSIVE scan of the NCHUNK chunk sums (in place).
// ---------------------------------------------------------------------------
__global__ __launch_bounds__(512) void chunk_scan_kernel(double* __restrict__ csum) {
    int r = blockIdx.x;
    int t = threadIdx.x;
    int lane = t & 63, w = t >> 6;
    double orig = (t < NCHUNK) ? csum[(long)r * NCHUNK + t] : 0.0;
    double v = orig;
    for (int off = 1; off < 64; off <<= 1) {
        double n = __shfl_up(v, off, 64);
        if (lane >= off) v += n;
    }
    __shared__ double wsum[8];
    if (lane == 63) wsum[w] = v;
    __syncthreads();
    double add = 0.0;
    for (int i = 0; i < w; ++i) add += wsum[i];
    v += add;
    if (t < NCHUNK) csum[(long)r * NCHUNK + t] = v - orig;   // exclusive prefix
}

// ---------------------------------------------------------------------------
// Kernel 3: per-sample phase nu (revolutions mod 1), hoisted out of osc.
// Bit-identical to the in-osc scan of the passing R2 kernel.
// ---------------------------------------------------------------------------
__global__ __launch_bounds__(128) void nu_kernel(
        const float* __restrict__ f0, const double* __restrict__ csum,
        const float* __restrict__ phase, float* __restrict__ nuarr) {
    int bx = blockIdx.x;                 // chunk id
    int r  = bx / NCHUNK;
    int t  = threadIdx.x;
    int lane = t & 63, w = t >> 6;
    long sbase = (long)bx * CHUNK;
    double v = (double)f0[sbase + t];
    for (int off = 1; off < 64; off <<= 1) {
        double n = __shfl_up(v, off, 64);
        if (lane >= off) v += n;
    }
    __shared__ double wsum[2];
    if (lane == 63) wsum[w] = v;
    __syncthreads();
    if (w == 1) v += wsum[0];
    v += csum[bx];
    double x = v * (1.0 / 44100.0) + (double)phase[r] * 0.15915494309189535;
    x -= floor(x);
    nuarr[sbase + t] = (float)x;         // [0,1)
}

// ---------------------------------------------------------------------------
// Kernel 4: persistent oscillator. 512 blocks x 512 threads, 2 blocks/CU.
// Each block grid-strides 31-32 chunks with double-buffered global_load_lds
// staging: issue chunk i+1's slab right after the barrier, compute chunk i
// with no internal barriers. One barrier per chunk; vmcnt drain hides under
// the full compute phase. Math identical to the passing R2 kernel.
// ---------------------------------------------------------------------------
__global__ __launch_bounds__(512, 4) void osc_kernel(
        const float* __restrict__ f0,
        const float* __restrict__ ha,
        const float* __restrict__ nuarr,
        const float* __restrict__ gtab,
        float* __restrict__ out) {
    int b = blockIdx.x;
    int t = threadIdx.x;
    int lane = t & 63, w = t >> 6;       // wave 0..7

    __shared__ float slab[2][CHUNK * 65];   // 2 x 33,280 B
    __shared__ float tab[TAB_N];            //     4,608 B

    // ---- stage table once per block (covered by first loop barrier) ----
    if (t < 288) ((float4*)tab)[t] = ((const float4*)gtab)[t];

    // blocks 0..127 process 32 chunks, the rest 31  (16000 = 31*512 + 128)
    int nIter = (b < (NCH_TOT - 31 * PBLOCKS)) ? 32 : 31;

    // stage one 33,280 B chunk slab into buf: 8 waves x 4 KB + 1 KB tail
    // (tail overlaps 512 B of wave 7's last round with identical data).
    auto stage = [&](int buf, int c) {
        const char* src = (const char*)ha + (long)c * (CHUNK * 65 * 4);
        char*       dst = (char*)slab[buf];
        #pragma unroll
        for (int k = 0; k < 4; ++k) {
            int rr = w + 8 * k;                       // rounds 0..31, 1 KB each
            GLOAD_LDS16(src + rr * 1024 + lane * 16,
                        dst + rr * 1024 + lane * 16);
        }
        if (w == 0)                                   // bytes 32,256..33,279
            GLOAD_LDS16(src + 32256 + lane * 16,
                        dst + 32256 + lane * 16);
    };

    stage(0, b);                                      // prefetch first chunk

    for (int i = 0; i < nIter; ++i) {
        int c = i * PBLOCKS + b;
        __syncthreads();                 // drains vmcnt: slab[i&1] ready; all
                                         // waves done with slab[(i-1)&1]
        if (i + 1 < nIter) stage((i + 1) & 1, c + PBLOCKS);

        // ---------------- compute on slab[i&1], no barriers ----------------
        const float* amp = slab[i & 1];
        long sbase = (long)c * CHUNK;
        int s  = w * 16 + (lane & 15);   // sample within chunk
        int q  = lane >> 4;              // harmonic quarter 0..3
        int h0 = q * 16;

        float f0v = f0[sbase + s];
        float nu  = nuarr[sbase + s];

        // exact anti-alias cutoff: max h with f0*h < 22050 (f32 semantics)
        float k0 = floorf(22050.0f / f0v);
        if (f0v * (k0 + 1.0f) < 22050.0f)      k0 += 1.0f;
        else if (!(f0v * k0 < 22050.0f))       k0 -= 1.0f;

        // Chebyshev init: sA=sin((h0+1)θ), sB=sin((h0+2)θ), c2=2cosθ
        float c2;
        {
            float th = 6.283185307179586f * nu;
            c2 = 2.0f * __cosf(th);
        }
        float m1 = (float)(h0 + 1) * nu; m1 -= floorf(m1);
        float m2 = (float)(h0 + 2) * nu; m2 -= floorf(m2);
        float sA = __sinf(6.283185307179586f * m1);
        float sB = __sinf(6.283185307179586f * m2);

        const float* arow = amp + s * 65 + 1 + h0;

        float S1 = 0.0f, S2 = 0.0f;
        #pragma unroll
        for (int j = 0; j < 16; j += 2) {
            float a0 = arow[j];
            float a1 = arow[j + 1];
            // scale_fn via table interp (identical math to passing kernel)
            float tc0 = fmaf(a0, 64.0f, 512.0f);
            tc0 = fminf(fmaxf(tc0, 0.0f), 1022.99f);
            float fi0 = floorf(tc0); int i0 = (int)fi0; float fr0 = tc0 - fi0;
            float w0 = fmaf(fr0, tab[i0 + 1] - tab[i0], tab[i0]);
            float tc1 = fmaf(a1, 64.0f, 512.0f);
            tc1 = fminf(fmaxf(tc1, 0.0f), 1022.99f);
            float fi1 = floorf(tc1); int i1 = (int)fi1; float fr1 = tc1 - fi1;
            float w1 = fmaf(fr1, tab[i1 + 1] - tab[i1], tab[i1]);

            w0 = ((float)(h0 + 1 + j) <= k0) ? w0 : 0.0f;
            w1 = ((float)(h0 + 2 + j) <= k0) ? w1 : 0.0f;

            S1 += w0; S2 = fmaf(w0, sA, S2);
            S1 += w1; S2 = fmaf(w1, sB, S2);

            float sn1 = fmaf(c2, sB, -sA);       // sin((h0+3+j)θ)
            float sn2 = fmaf(c2, sn1, -sB);      // sin((h0+4+j)θ)
            sA = sn1; sB = sn2;
        }

        // combine the 4 harmonic quarters of each sample
        S1 += __shfl_xor(S1, 16, 64);
        S1 += __shfl_xor(S1, 32, 64);
        S2 += __shfl_xor(S2, 16, 64);
        S2 += __shfl_xor(S2, 32, 64);

        if (q == 0) {
            float total = scale_fn(amp[s * 65]);       // exact, once per sample
            out[sbase + s] = total * S2 / (S1 + 1e-5f);
        }
    }
}

// ---------------------------------------------------------------------------
extern "C" void kernel_launch(void* const* d_in, const int* in_sizes, int n_in,
                              void* d_out, int out_size, void* d_ws, size_t ws_size,
                              hipStream_t stream) {
    (void)in_sizes; (void)n_in; (void)out_size; (void)ws_size;
    const float* f0    = (const float*)d_in[0];   // (32, 64000)
    const float* ha    = (const float*)d_in[1];   // (32, 64000, 65)
    const float* phase = (const float*)d_in[2];   // (32,)
    float* out = (float*)d_out;                   // (32, 64000)

    double* csum = (double*)d_ws;                               // 128,000 B
    float*  gtab = (float*)((char*)d_ws + 131072);              //   4,608 B
    float*  nuarr = (float*)((char*)d_ws + 262144);             // 8,192,000 B

    table_kernel<<<(TAB_N + 127) / 128, 128, 0, stream>>>(gtab);
    chunk_sum_kernel<<<NCH_TOT, CHUNK, 0, stream>>>(f0, csum);
    chunk_scan_kernel<<<BATCH, 512, 0, stream>>>(csum);
    nu_kernel<<<NCH_TOT, CHUNK, 0, stream>>>(f0, csum, phase, nuarr);
    osc_kernel<<<PBLOCKS, 512, 0, stream>>>(f0, ha, nuarr, gtab, out);
}